// Round 2
// baseline (457.381 us; speedup 1.0000x reference)
//
#include <hip/hip_runtime.h>
#include <hip/hip_bf16.h>

// Shapes fixed by the reference: B=8, T=2048, D=1024.
#define BB 8
#define TT 2048
#define DD 1024

typedef __attribute__((ext_vector_type(8))) short short8;
typedef __attribute__((ext_vector_type(4))) float f32x4;
typedef __attribute__((ext_vector_type(4))) unsigned short u16x4;

__device__ inline void gload_lds16(const void* g, void* l) {
    // async global->LDS, width 16B: dest = wave-uniform base + lane*16
    __builtin_amdgcn_global_load_lds((const __attribute__((address_space(1))) void*)g,
                                     (__attribute__((address_space(3))) void*)l, 16, 0, 0);
}

__device__ inline void store_c(float* p, float v) { *p = v; }
__device__ inline void store_c(__hip_bfloat16* p, float v) { *p = __float2bfloat16(v); }

// ---------------------------------------------------------------------------
// Generic 128x128-tile bf16 MFMA GEMM:  C[z] = A[z] (MxK, row-major, lda)
//                                           x  B[z] (KxN given as B^T NxK row-major, ldb)
// 4 waves, each 64x64 (4x4 tiles of 16x16x32 MFMA). global_load_lds width-16
// staging, XOR chunk swizzle to reduce ds_read_b128 bank conflicts.
// causalSkip: skip blocks fully above diagonal (n0 > m0).
// causalKStop: K-loop stops at m0+128 (rows only attend to keys <= row).
// ---------------------------------------------------------------------------
template<typename CT>
__global__ __launch_bounds__(256, 2) void gemm_bt(
    const __hip_bfloat16* __restrict__ Abase,
    const __hip_bfloat16* __restrict__ Btbase,
    void* __restrict__ Cbase,
    int M, int N, int K,
    int lda, int ldb, int ldc,
    long long sA, long long sB, long long sC,
    float scale, int causalSkip, int causalKStop)
{
    const int m0 = blockIdx.y * 128;
    const int n0 = blockIdx.x * 128;
    if (causalSkip && n0 > m0) return;   // tiles are 128-aligned: n0>m0 => fully masked

    const int z = blockIdx.z;
    const __hip_bfloat16* A  = Abase  + (size_t)z * sA;
    const __hip_bfloat16* Bt = Btbase + (size_t)z * sB;

    __shared__ __align__(16) __hip_bfloat16 lsA[128 * 32];
    __shared__ __align__(16) __hip_bfloat16 lsB[128 * 32];

    const int t    = threadIdx.x;
    const int w    = t >> 6;
    const int l    = t & 63;
    const int quad = l >> 4;
    const int l16  = l & 15;
    const int wy   = w >> 1;   // wave row (0..1), wave tile 64x64
    const int wx   = w & 1;    // wave col

    int kmax = K;
    if (causalKStop) { int km = m0 + 128; kmax = km < K ? km : K; }

    f32x4 acc[4][4];
#pragma unroll
    for (int i = 0; i < 4; i++)
#pragma unroll
        for (int j = 0; j < 4; j++) acc[i][j] = f32x4{0.f, 0.f, 0.f, 0.f};

    for (int k0 = 0; k0 < kmax; k0 += 32) {
        // ---- stage A (128x32) and Bt (128x32) into LDS, 16B per lane ----
        // LDS slot c (row=c>>2, sch=c&3) holds global chunk gch = sch ^ (row&3)
#pragma unroll
        for (int p = 0; p < 2; p++) {
            int c    = p * 256 + t;
            int row  = c >> 2;
            int gch  = (c & 3) ^ (row & 3);
            const __hip_bfloat16* ga = A  + (size_t)(m0 + row) * lda + (k0 + gch * 8);
            const __hip_bfloat16* gb = Bt + (size_t)(n0 + row) * ldb + (k0 + gch * 8);
            char* la = (char*)lsA + p * 4096 + w * 1024;
            char* lb = (char*)lsB + p * 4096 + w * 1024;
            gload_lds16(ga, la);
            gload_lds16(gb, lb);
        }
        __syncthreads();   // drains vmcnt (async LDS loads) + barrier

        short8 aF[4], bF[4];
#pragma unroll
        for (int mf = 0; mf < 4; mf++) {
            int m = wy * 64 + mf * 16 + l16;
            aF[mf] = *(const short8*)((const char*)lsA + m * 64 + ((quad ^ (m & 3)) * 16));
        }
#pragma unroll
        for (int nf = 0; nf < 4; nf++) {
            int n = wx * 64 + nf * 16 + l16;
            bF[nf] = *(const short8*)((const char*)lsB + n * 64 + ((quad ^ (n & 3)) * 16));
        }
#pragma unroll
        for (int mf = 0; mf < 4; mf++)
#pragma unroll
            for (int nf = 0; nf < 4; nf++)
                acc[mf][nf] = __builtin_amdgcn_mfma_f32_16x16x32_bf16(
                    aF[mf], bF[nf], acc[mf][nf], 0, 0, 0);
        __syncthreads();   // all waves done reading LDS before next stage
    }

    // ---- epilogue: C/D layout col = lane&15, row = quad*4 + reg ----
    CT* C = (CT*)Cbase + (size_t)z * sC;
#pragma unroll
    for (int mf = 0; mf < 4; mf++) {
        int rbase = m0 + wy * 64 + mf * 16 + quad * 4;
#pragma unroll
        for (int nf = 0; nf < 4; nf++) {
            int col = n0 + wx * 64 + nf * 16 + l16;
#pragma unroll
            for (int r = 0; r < 4; r++)
                store_c(&C[(size_t)(rbase + r) * ldc + col], acc[mf][nf][r] * scale);
        }
    }
}

// ---------------------------------------------------------------------------
// x (fp32) -> bf16, 4 elems/thread vectorized
// ---------------------------------------------------------------------------
__global__ __launch_bounds__(256) void cvt_x(const float* __restrict__ in,
                                             unsigned short* __restrict__ out)
{
    size_t i = ((size_t)blockIdx.x * 256 + threadIdx.x) * 4;
    float4 f = *(const float4*)(in + i);
    union { u16x4 u; __hip_bfloat16 h[4]; } o;
    o.h[0] = __float2bfloat16(f.x);
    o.h[1] = __float2bfloat16(f.y);
    o.h[2] = __float2bfloat16(f.z);
    o.h[3] = __float2bfloat16(f.w);
    *(u16x4*)(out + i) = o.u;
}

// ---------------------------------------------------------------------------
// W (DxD fp32, row-major [c][h]) -> Wt (bf16, [h][c]); z selects Wk/Wq/Wv
// ---------------------------------------------------------------------------
__global__ __launch_bounds__(256) void transpose_cvt_w(
    const float* __restrict__ Wk, const float* __restrict__ Wq,
    const float* __restrict__ Wv, __hip_bfloat16* __restrict__ Wt)
{
    const float* W = blockIdx.z == 0 ? Wk : (blockIdx.z == 1 ? Wq : Wv);
    __hip_bfloat16* o = Wt + (size_t)blockIdx.z * DD * DD;
    int h0 = blockIdx.x * 32, c0 = blockIdx.y * 32;
    __shared__ float tl[32][33];
    int tx = threadIdx.x, ty = threadIdx.y;
#pragma unroll
    for (int k = 0; k < 4; k++)
        tl[ty + 8 * k][tx] = W[(size_t)(c0 + ty + 8 * k) * DD + h0 + tx];
    __syncthreads();
#pragma unroll
    for (int k = 0; k < 4; k++)
        o[(size_t)(h0 + ty + 8 * k) * DD + c0 + tx] = __float2bfloat16(tl[tx][ty + 8 * k]);
}

// ---------------------------------------------------------------------------
// Causal row softmax over S (fp32), IN-PLACE: writes P (bf16) over the first
// half of each row's bytes. One block per row. All reads of the row complete
// before the block-wide barrier; all writes happen after it -> no race.
// P row i is zero-padded up to the next 128 boundary (PV GEMM reads that far).
// ---------------------------------------------------------------------------
__global__ __launch_bounds__(256) void softmax_causal(float* __restrict__ S)
{
    int row = blockIdx.x;
    int b = row >> 11;           // local batch within group
    int i = row & (TT - 1);
    float* s = S + (size_t)b * TT * TT + (size_t)i * TT;
    __hip_bfloat16* p = (__hip_bfloat16*)s;   // in-place bf16 row (2048 elems = 4096 B)
    int len = i + 1;
    int t = threadIdx.x;

    float v[8];
    float mx = -1e30f;
#pragma unroll
    for (int j = 0; j < 8; j++) {
        int idx = t + j * 256;
        v[j] = (idx < len) ? s[idx] : -1e30f;
        mx = fmaxf(mx, v[j]);
    }
#pragma unroll
    for (int off = 32; off; off >>= 1) mx = fmaxf(mx, __shfl_down(mx, off, 64));
    __shared__ float red[4], red2[4];
    if ((t & 63) == 0) red[t >> 6] = mx;
    __syncthreads();
    mx = fmaxf(fmaxf(red[0], red[1]), fmaxf(red[2], red[3]));

    float sum = 0.f;
#pragma unroll
    for (int j = 0; j < 8; j++) {
        int idx = t + j * 256;
        float e = (idx < len) ? __expf(v[j] - mx) : 0.f;
        v[j] = e;
        sum += e;
    }
#pragma unroll
    for (int off = 32; off; off >>= 1) sum += __shfl_down(sum, off, 64);
    if ((t & 63) == 0) red2[t >> 6] = sum;
    __syncthreads();               // ALSO separates all S-reads from P-writes
    sum = red2[0] + red2[1] + red2[2] + red2[3];
    float inv = 1.f / sum;

    int pad_end = ((i >> 7) + 1) << 7;   // PV GEMM reads cols < m0+128 == this
#pragma unroll
    for (int j = 0; j < 8; j++) {
        int idx = t + j * 256;
        if (idx < pad_end)
            p[idx] = __float2bfloat16(idx < len ? v[j] * inv : 0.f);
    }
}

// ---------------------------------------------------------------------------
extern "C" void kernel_launch(void* const* d_in, const int* in_sizes, int n_in,
                              void* d_out, int out_size, void* d_ws, size_t ws_size,
                              hipStream_t stream)
{
    const float* x  = (const float*)d_in[0];
    const float* Wk = (const float*)d_in[1];
    const float* Wq = (const float*)d_in[2];
    const float* Wv = (const float*)d_in[3];
    float* out = (float*)d_out;

    // workspace layout (bytes) — min footprint 140,509,184 B (134 MiB):
    //   k   @ 0           : 16,777,216 bf16  (33,554,432 B)
    //   q   @  33,554,432 : 16,777,216 bf16  (33,554,432 B)
    //   vT2 @  67,108,864 : 1024x16384 bf16  (33,554,432 B)   [d][b*T+t]
    //   wt  @ 100,663,296 : 3x1,048,576 bf16 ( 6,291,456 B)   [k,q,v order]
    //   xb  @ 106,954,752 : 16,777,216 bf16  (33,554,432 B)
    //   S   @ 106,954,752 : g x 2048x2048 f32 (g*16,777,216 B) — OVERLAYS xb,
    //        live only after the projection GEMMs; P (bf16) aliases S in place.
    char* ws = (char*)d_ws;
    __hip_bfloat16* kq  = (__hip_bfloat16*)ws;                    // k then q
    __hip_bfloat16* kk  = kq;
    __hip_bfloat16* qq  = kq + 16777216;
    __hip_bfloat16* vT2 = (__hip_bfloat16*)(ws + 67108864);
    __hip_bfloat16* wt  = (__hip_bfloat16*)(ws + 100663296);
    __hip_bfloat16* xb  = (__hip_bfloat16*)(ws + 106954752);
    float*          S   = (float*)         (ws + 106954752);

    // batch group size: largest g whose S region fits in ws (deterministic per ws_size)
    const size_t S_off = 106954752ull;
    int g = (ws_size >= S_off + 8ull * 16777216ull) ? 8
          : (ws_size >= S_off + 4ull * 16777216ull) ? 4 : 2;

    // 1. convert inputs to bf16 (W transposed to B^T layout)
    cvt_x<<<16384, 256, 0, stream>>>(x, (unsigned short*)xb);
    transpose_cvt_w<<<dim3(32, 32, 3), dim3(32, 8), 0, stream>>>(Wk, Wq, Wv, wt);

    // 2. K,Q = x @ W{k,q}   (M=16384, N=1024, K=1024; z selects matrix)
    gemm_bt<__hip_bfloat16><<<dim3(8, 128, 2), 256, 0, stream>>>(
        xb, wt, kq, 16384, 1024, 1024, 1024, 1024, 1024,
        0LL, 1048576LL, 16777216LL, 1.0f, 0, 0);

    // 3. vT2 = Wv^T @ x^T  -> [d][b*T+t] directly (no separate transpose pass)
    gemm_bt<__hip_bfloat16><<<dim3(128, 8, 1), 256, 0, stream>>>(
        wt + 2 * 1048576, xb, vT2, 1024, 16384, 1024, 1024, 1024, 16384,
        0LL, 0LL, 0LL, 1.0f, 0, 0);

    // 4..6 per batch group
    for (int g0 = 0; g0 < BB; g0 += g) {
        // 4. S = Q K^T * (1/32), skipping above-diagonal blocks
        gemm_bt<float><<<dim3(16, 16, g), 256, 0, stream>>>(
            qq + (size_t)g0 * 2097152, kk + (size_t)g0 * 2097152, S,
            2048, 2048, 1024, 1024, 1024, 2048,
            2097152LL, 2097152LL, 4194304LL, 0.03125f, 1, 0);

        // 5. P = causal softmax(S), bf16, in place over S
        softmax_causal<<<g * 2048, 256, 0, stream>>>(S);

        // 6. out = P @ V  (P read from S buffer: lda=4096 bf16 = fp32 row pitch;
        //    vT2 batch view: col offset g0*2048, row stride 16384; causal K-stop)
        gemm_bt<float><<<dim3(8, 16, g), 256, 0, stream>>>(
            (const __hip_bfloat16*)S, vT2 + (size_t)g0 * 2048,
            out + (size_t)g0 * 2097152,
            2048, 1024, 2048, 4096, 16384, 1024,
            8388608LL, 2048LL, 2097152LL, 1.0f, 0, 1);
    }
}

// Round 3
// 403.365 us; speedup vs baseline: 1.1339x; 1.1339x over previous
//
#include <hip/hip_runtime.h>
#include <hip/hip_bf16.h>

// Shapes fixed by the reference: B=8, T=2048, D=1024.
#define BB 8
#define TT 2048
#define DD 1024

typedef __attribute__((ext_vector_type(8))) short short8;
typedef __attribute__((ext_vector_type(4))) float f32x4;
typedef __attribute__((ext_vector_type(4))) unsigned short u16x4;

__device__ inline void gload_lds16(const void* g, void* l) {
    // async global->LDS, width 16B: dest = wave-uniform base + lane*16
    __builtin_amdgcn_global_load_lds((const __attribute__((address_space(1))) void*)g,
                                     (__attribute__((address_space(3))) void*)l, 16, 0, 0);
}

__device__ inline void store_c(float* p, float v) { *p = v; }
__device__ inline void store_c(__hip_bfloat16* p, float v) { *p = __float2bfloat16(v); }

// ---------------------------------------------------------------------------
// 128x128-tile bf16 MFMA GEMM, BK=64:  C[z] = A[z] (MxK row-major, lda)
//                                          x  B[z] (given as B^T, NxK row-major, ldb)
// 4 waves x (64x64 each, 4x4 tiles of 16x16x32 MFMA). global_load_lds width-16
// staging (4 rounds per matrix per iter), XOR chunk swizzle (8 chunks/row).
// swapMN: m-tile on blockIdx.x (fast dim) so same-A-panel blocks share an XCD.
// causalSkip: skip blocks fully above diagonal. causalKStop: kmax = m0+128.
// ---------------------------------------------------------------------------
template<typename CT>
__global__ __launch_bounds__(256, 3) void gemm_bt(
    const __hip_bfloat16* __restrict__ Abase,
    const __hip_bfloat16* __restrict__ Btbase,
    void* __restrict__ Cbase,
    int K, int lda, int ldb, int ldc,
    long long sA, long long sB, long long sC,
    float scale, int causalSkip, int causalKStop, int swapMN)
{
    const int m0 = (swapMN ? blockIdx.x : blockIdx.y) * 128;
    const int n0 = (swapMN ? blockIdx.y : blockIdx.x) * 128;
    if (causalSkip && n0 > m0) return;   // 128-aligned tiles: n0>m0 => fully masked

    const int z = blockIdx.z;
    const __hip_bfloat16* A  = Abase  + (size_t)z * sA;
    const __hip_bfloat16* Bt = Btbase + (size_t)z * sB;

    // 128 rows x 64 cols bf16 = 128 B/row = 8 chunks of 16 B, XOR-swizzled:
    // LDS slot (row, s) holds global chunk s ^ (row&7).
    __shared__ __align__(16) __hip_bfloat16 lsA[128 * 64];
    __shared__ __align__(16) __hip_bfloat16 lsB[128 * 64];

    const int t    = threadIdx.x;
    const int w    = t >> 6;
    const int l    = t & 63;
    const int quad = l >> 4;
    const int l16  = l & 15;
    const int wy   = w >> 1;   // wave row (0..1), wave tile 64x64
    const int wx   = w & 1;    // wave col

    int kmax = K;
    if (causalKStop) { int km = m0 + 128; kmax = km < K ? km : K; }

    f32x4 acc[4][4];
#pragma unroll
    for (int i = 0; i < 4; i++)
#pragma unroll
        for (int j = 0; j < 4; j++) acc[i][j] = f32x4{0.f, 0.f, 0.f, 0.f};

    for (int k0 = 0; k0 < kmax; k0 += 64) {
        // ---- stage A (128x64) and Bt (128x64): 4 rounds x 256 lanes x 16B each ----
#pragma unroll
        for (int p = 0; p < 4; p++) {
            int c   = p * 256 + t;          // slot index 0..1023
            int row = c >> 3;               // 8 slots (chunks) per row
            int gch = (c & 7) ^ (row & 7);  // global chunk stored at this slot
            const __hip_bfloat16* ga = A  + (size_t)(m0 + row) * lda + (k0 + gch * 8);
            const __hip_bfloat16* gb = Bt + (size_t)(n0 + row) * ldb + (k0 + gch * 8);
            char* la = (char*)lsA + p * 4096 + w * 1024;   // slot*16, wave-uniform base
            char* lb = (char*)lsB + p * 4096 + w * 1024;
            gload_lds16(ga, la);
            gload_lds16(gb, lb);
        }
        __syncthreads();   // drains vmcnt (async LDS loads) + barrier

#pragma unroll
        for (int h = 0; h < 2; h++) {      // two K=32 halves of the 64-wide tile
            short8 aF[4], bF[4];
#pragma unroll
            for (int mf = 0; mf < 4; mf++) {
                int m = wy * 64 + mf * 16 + l16;
                aF[mf] = *(const short8*)((const char*)lsA + m * 128 +
                                          (((h * 4 + quad) ^ (m & 7)) * 16));
            }
#pragma unroll
            for (int nf = 0; nf < 4; nf++) {
                int n = wx * 64 + nf * 16 + l16;
                bF[nf] = *(const short8*)((const char*)lsB + n * 128 +
                                          (((h * 4 + quad) ^ (n & 7)) * 16));
            }
#pragma unroll
            for (int mf = 0; mf < 4; mf++)
#pragma unroll
                for (int nf = 0; nf < 4; nf++)
                    acc[mf][nf] = __builtin_amdgcn_mfma_f32_16x16x32_bf16(
                        aF[mf], bF[nf], acc[mf][nf], 0, 0, 0);
        }
        __syncthreads();   // all waves done reading LDS before next stage
    }

    // ---- epilogue: C/D layout col = lane&15, row = quad*4 + reg ----
    CT* C = (CT*)Cbase + (size_t)z * sC;
#pragma unroll
    for (int mf = 0; mf < 4; mf++) {
        int rbase = m0 + wy * 64 + mf * 16 + quad * 4;
#pragma unroll
        for (int nf = 0; nf < 4; nf++) {
            int col = n0 + wx * 64 + nf * 16 + l16;
#pragma unroll
            for (int r = 0; r < 4; r++)
                store_c(&C[(size_t)(rbase + r) * ldc + col], acc[mf][nf][r] * scale);
        }
    }
}

// ---------------------------------------------------------------------------
// x (fp32) -> bf16, 4 elems/thread vectorized
// ---------------------------------------------------------------------------
__global__ __launch_bounds__(256) void cvt_x(const float* __restrict__ in,
                                             unsigned short* __restrict__ out)
{
    size_t i = ((size_t)blockIdx.x * 256 + threadIdx.x) * 4;
    float4 f = *(const float4*)(in + i);
    union { u16x4 u; __hip_bfloat16 h[4]; } o;
    o.h[0] = __float2bfloat16(f.x);
    o.h[1] = __float2bfloat16(f.y);
    o.h[2] = __float2bfloat16(f.z);
    o.h[3] = __float2bfloat16(f.w);
    *(u16x4*)(out + i) = o.u;
}

// ---------------------------------------------------------------------------
// W (DxD fp32, row-major [c][h]) -> Wt (bf16, [h][c]); z selects Wk/Wq/Wv
// ---------------------------------------------------------------------------
__global__ __launch_bounds__(256) void transpose_cvt_w(
    const float* __restrict__ Wk, const float* __restrict__ Wq,
    const float* __restrict__ Wv, __hip_bfloat16* __restrict__ Wt)
{
    const float* W = blockIdx.z == 0 ? Wk : (blockIdx.z == 1 ? Wq : Wv);
    __hip_bfloat16* o = Wt + (size_t)blockIdx.z * DD * DD;
    int h0 = blockIdx.x * 32, c0 = blockIdx.y * 32;
    __shared__ float tl[32][33];
    int tx = threadIdx.x, ty = threadIdx.y;
#pragma unroll
    for (int k = 0; k < 4; k++)
        tl[ty + 8 * k][tx] = W[(size_t)(c0 + ty + 8 * k) * DD + h0 + tx];
    __syncthreads();
#pragma unroll
    for (int k = 0; k < 4; k++)
        o[(size_t)(h0 + ty + 8 * k) * DD + c0 + tx] = __float2bfloat16(tl[tx][ty + 8 * k]);
}

// ---------------------------------------------------------------------------
// Causal row softmax over S (fp32), IN-PLACE: writes P (bf16) over the first
// half of each row's bytes. One block per row. All reads of the row complete
// before the block-wide barrier; all writes happen after it -> no race.
// P row i is zero-padded up to the next 128 boundary (PV GEMM reads that far).
// ---------------------------------------------------------------------------
__global__ __launch_bounds__(256) void softmax_causal(float* __restrict__ S)
{
    int row = blockIdx.x;
    int b = row >> 11;           // local batch within group
    int i = row & (TT - 1);
    float* s = S + (size_t)b * TT * TT + (size_t)i * TT;
    __hip_bfloat16* p = (__hip_bfloat16*)s;   // in-place bf16 row (2048 elems = 4096 B)
    int len = i + 1;
    int t = threadIdx.x;

    float v[8];
    float mx = -1e30f;
#pragma unroll
    for (int j = 0; j < 8; j++) {
        int idx = t + j * 256;
        v[j] = (idx < len) ? s[idx] : -1e30f;
        mx = fmaxf(mx, v[j]);
    }
#pragma unroll
    for (int off = 32; off; off >>= 1) mx = fmaxf(mx, __shfl_down(mx, off, 64));
    __shared__ float red[4], red2[4];
    if ((t & 63) == 0) red[t >> 6] = mx;
    __syncthreads();
    mx = fmaxf(fmaxf(red[0], red[1]), fmaxf(red[2], red[3]));

    float sum = 0.f;
#pragma unroll
    for (int j = 0; j < 8; j++) {
        int idx = t + j * 256;
        float e = (idx < len) ? __expf(v[j] - mx) : 0.f;
        v[j] = e;
        sum += e;
    }
#pragma unroll
    for (int off = 32; off; off >>= 1) sum += __shfl_down(sum, off, 64);
    if ((t & 63) == 0) red2[t >> 6] = sum;
    __syncthreads();               // ALSO separates all S-reads from P-writes
    sum = red2[0] + red2[1] + red2[2] + red2[3];
    float inv = 1.f / sum;

    int pad_end = ((i >> 7) + 1) << 7;   // PV GEMM reads cols < m0+128 == this
#pragma unroll
    for (int j = 0; j < 8; j++) {
        int idx = t + j * 256;
        if (idx < pad_end)
            p[idx] = __float2bfloat16(idx < len ? v[j] * inv : 0.f);
    }
}

// ---------------------------------------------------------------------------
extern "C" void kernel_launch(void* const* d_in, const int* in_sizes, int n_in,
                              void* d_out, int out_size, void* d_ws, size_t ws_size,
                              hipStream_t stream)
{
    const float* x  = (const float*)d_in[0];
    const float* Wk = (const float*)d_in[1];
    const float* Wq = (const float*)d_in[2];
    const float* Wv = (const float*)d_in[3];
    float* out = (float*)d_out;

    // workspace layout (bytes) — min footprint 140,509,184 B (134 MiB):
    //   k   @ 0           : 16,777,216 bf16  (33,554,432 B)
    //   q   @  33,554,432 : 16,777,216 bf16  (33,554,432 B)
    //   vT2 @  67,108,864 : 1024x16384 bf16  (33,554,432 B)   [d][b*T+t]
    //   wt  @ 100,663,296 : 3x1,048,576 bf16 ( 6,291,456 B)   [k,q,v order]
    //   xb  @ 106,954,752 : 16,777,216 bf16  (33,554,432 B)
    //   S   @ 106,954,752 : g x 2048x2048 f32 (g*16,777,216 B) — OVERLAYS xb,
    //        live only after the projection GEMMs; P (bf16) aliases S in place.
    char* ws = (char*)d_ws;
    __hip_bfloat16* kq  = (__hip_bfloat16*)ws;                    // k then q
    __hip_bfloat16* kk  = kq;
    __hip_bfloat16* qq  = kq + 16777216;
    __hip_bfloat16* vT2 = (__hip_bfloat16*)(ws + 67108864);
    __hip_bfloat16* wt  = (__hip_bfloat16*)(ws + 100663296);
    __hip_bfloat16* xb  = (__hip_bfloat16*)(ws + 106954752);
    float*          S   = (float*)         (ws + 106954752);

    // batch group size: largest g whose S region fits in ws (deterministic per ws_size)
    const size_t S_off = 106954752ull;
    int g = (ws_size >= S_off + 8ull * 16777216ull) ? 8
          : (ws_size >= S_off + 4ull * 16777216ull) ? 4 : 2;

    // 1. convert inputs to bf16 (W transposed to B^T layout)
    cvt_x<<<16384, 256, 0, stream>>>(x, (unsigned short*)xb);
    transpose_cvt_w<<<dim3(32, 32, 3), dim3(32, 8), 0, stream>>>(Wk, Wq, Wv, wt);

    // 2. K,Q = x @ W{k,q}  (M=16384,N=1024,K=1024). swapMN=1: m-tile on fast grid
    //    dim -> same-A-panel blocks land on one XCD; A fetched once per XCD-L2.
    gemm_bt<__hip_bfloat16><<<dim3(128, 8, 2), 256, 0, stream>>>(
        xb, wt, kq, 1024, 1024, 1024, 1024,
        0LL, 1048576LL, 16777216LL, 1.0f, 0, 0, 1);

    // 3. vT2 = Wv^T @ x^T -> [d][b*T+t] directly. Fast dim = N-tiles (big xb
    //    operand) already XCD-local -> swapMN=0.
    gemm_bt<__hip_bfloat16><<<dim3(128, 8, 1), 256, 0, stream>>>(
        wt + 2 * 1048576, xb, vT2, 1024, 1024, 1024, 16384,
        0LL, 0LL, 0LL, 1.0f, 0, 0, 0);

    // 4..6 per batch group
    for (int g0 = 0; g0 < BB; g0 += g) {
        // 4. S = Q K^T * (1/32), skipping above-diagonal blocks
        gemm_bt<float><<<dim3(16, 16, g), 256, 0, stream>>>(
            qq + (size_t)g0 * 2097152, kk + (size_t)g0 * 2097152, S,
            1024, 1024, 1024, 2048,
            2097152LL, 2097152LL, 4194304LL, 0.03125f, 1, 0, 0);

        // 5. P = causal softmax(S), bf16, in place over S
        softmax_causal<<<g * 2048, 256, 0, stream>>>(S);

        // 6. out = P @ V  (P read from S buffer: lda=4096 bf16 = fp32 row pitch;
        //    vT2 batch view: col offset g0*2048, row stride 16384; causal K-stop).
        //    swapMN=1: P-panels (the big operand) XCD-local.
        gemm_bt<float><<<dim3(16, 8, g), 256, 0, stream>>>(
            (const __hip_bfloat16*)S, vT2 + (size_t)g0 * 2048,
            out + (size_t)g0 * 2097152,
            2048, 4096, 16384, 1024,
            8388608LL, 2048LL, 2097152LL, 1.0f, 0, 1, 1);
    }
}

// Round 4
// 364.413 us; speedup vs baseline: 1.2551x; 1.1069x over previous
//
#include <hip/hip_runtime.h>
#include <hip/hip_bf16.h>

// Shapes fixed by the reference: B=8, T=2048, D=1024.
#define BB 8
#define TT 2048
#define DD 1024

typedef __attribute__((ext_vector_type(8))) short short8;
typedef __attribute__((ext_vector_type(4))) float f32x4;
typedef __attribute__((ext_vector_type(4))) unsigned short u16x4;

__device__ inline void gload_lds16(const void* g, void* l) {
    // async global->LDS, width 16B: dest = wave-uniform base + lane*16
    __builtin_amdgcn_global_load_lds((const __attribute__((address_space(1))) void*)g,
                                     (__attribute__((address_space(3))) void*)l, 16, 0, 0);
}

// ---------------------------------------------------------------------------
// 128x128-tile bf16 MFMA GEMM, BK=64:  C[z] = A[z] (MxK row-major, lda)
//                                          x  B[z] (given as B^T, NxK row-major, ldb)
// 4 waves x (64x64 each, 4x4 tiles of 16x16x32 MFMA). global_load_lds width-16
// staging, XOR chunk swizzle (8 chunks/row) -> 0 LDS bank conflicts (r3 PMC).
// swapMN: m-tile on blockIdx.x (fast dim) so same-A-panel blocks share an XCD.
// causalSkip: skip blocks fully above diagonal. causalKStop: kmax = m0+128.
// MODE 0: C[CT] = scale * acc
// MODE 1: C[bf16] = exp(scale*acc) causal-masked; atomicAdd row sums into aux
// MODE 2: C[f32] = acc / aux[row]  (softmax normalization folded in)
// ---------------------------------------------------------------------------
template<int MODE, typename CT>
__global__ __launch_bounds__(256, 3) void gemm_bt(
    const __hip_bfloat16* __restrict__ Abase,
    const __hip_bfloat16* __restrict__ Btbase,
    void* __restrict__ Cbase,
    int K, int lda, int ldb, int ldc,
    long long sA, long long sB, long long sC,
    float scale, int causalSkip, int causalKStop, int swapMN,
    float* __restrict__ aux)
{
    const int m0 = (swapMN ? blockIdx.x : blockIdx.y) * 128;
    const int n0 = (swapMN ? blockIdx.y : blockIdx.x) * 128;
    if (causalSkip && n0 > m0) return;   // 128-aligned tiles: n0>m0 => fully masked

    const int z = blockIdx.z;
    const __hip_bfloat16* A  = Abase  + (size_t)z * sA;
    const __hip_bfloat16* Bt = Btbase + (size_t)z * sB;

    // 128 rows x 64 cols bf16 = 128 B/row = 8 chunks of 16 B, XOR-swizzled:
    // LDS slot (row, s) holds global chunk s ^ (row&7).
    __shared__ __align__(16) __hip_bfloat16 lsA[128 * 64];
    __shared__ __align__(16) __hip_bfloat16 lsB[128 * 64];

    const int t    = threadIdx.x;
    const int w    = t >> 6;
    const int l    = t & 63;
    const int quad = l >> 4;
    const int l16  = l & 15;
    const int wy   = w >> 1;   // wave row (0..1), wave tile 64x64
    const int wx   = w & 1;    // wave col

    int kmax = K;
    if (causalKStop) { int km = m0 + 128; kmax = km < K ? km : K; }

    f32x4 acc[4][4];
#pragma unroll
    for (int i = 0; i < 4; i++)
#pragma unroll
        for (int j = 0; j < 4; j++) acc[i][j] = f32x4{0.f, 0.f, 0.f, 0.f};

    for (int k0 = 0; k0 < kmax; k0 += 64) {
        // ---- stage A (128x64) and Bt (128x64): 4 rounds x 256 lanes x 16B each ----
#pragma unroll
        for (int p = 0; p < 4; p++) {
            int c   = p * 256 + t;          // slot index 0..1023
            int row = c >> 3;               // 8 slots (chunks) per row
            int gch = (c & 7) ^ (row & 7);  // global chunk stored at this slot
            const __hip_bfloat16* ga = A  + (size_t)(m0 + row) * lda + (k0 + gch * 8);
            const __hip_bfloat16* gb = Bt + (size_t)(n0 + row) * ldb + (k0 + gch * 8);
            char* la = (char*)lsA + p * 4096 + w * 1024;   // slot*16, wave-uniform base
            char* lb = (char*)lsB + p * 4096 + w * 1024;
            gload_lds16(ga, la);
            gload_lds16(gb, lb);
        }
        __syncthreads();   // drains vmcnt (async LDS loads) + barrier

#pragma unroll
        for (int h = 0; h < 2; h++) {      // two K=32 halves of the 64-wide tile
            short8 aF[4], bF[4];
#pragma unroll
            for (int mf = 0; mf < 4; mf++) {
                int m = wy * 64 + mf * 16 + l16;
                aF[mf] = *(const short8*)((const char*)lsA + m * 128 +
                                          (((h * 4 + quad) ^ (m & 7)) * 16));
            }
#pragma unroll
            for (int nf = 0; nf < 4; nf++) {
                int n = wx * 64 + nf * 16 + l16;
                bF[nf] = *(const short8*)((const char*)lsB + n * 128 +
                                          (((h * 4 + quad) ^ (n & 7)) * 16));
            }
#pragma unroll
            for (int mf = 0; mf < 4; mf++)
#pragma unroll
                for (int nf = 0; nf < 4; nf++)
                    acc[mf][nf] = __builtin_amdgcn_mfma_f32_16x16x32_bf16(
                        aF[mf], bF[nf], acc[mf][nf], 0, 0, 0);
        }
        __syncthreads();   // all waves done reading LDS before next stage
    }

    // ---- epilogue: C/D layout col = lane&15, row = quad*4 + reg ----
    if constexpr (MODE == 0) {
        CT* C = (CT*)Cbase + (size_t)z * sC;
#pragma unroll
        for (int mf = 0; mf < 4; mf++) {
            int rbase = m0 + wy * 64 + mf * 16 + quad * 4;
#pragma unroll
            for (int nf = 0; nf < 4; nf++) {
                int col = n0 + wx * 64 + nf * 16 + l16;
#pragma unroll
                for (int r = 0; r < 4; r++) {
                    float v = acc[mf][nf][r] * scale;
                    if constexpr (sizeof(CT) == 2)
                        C[(size_t)(rbase + r) * ldc + col] = (CT)__float2bfloat16(v);
                    else
                        *((float*)&C[(size_t)(rbase + r) * ldc + col]) = v;
                }
            }
        }
    } else if constexpr (MODE == 1) {
        // exp + causal mask + per-row partial sums (softmax numerator)
        __hip_bfloat16* C = (__hip_bfloat16*)Cbase + (size_t)z * sC;
        float* rs = aux + (size_t)z * TT;
#pragma unroll
        for (int mf = 0; mf < 4; mf++) {
            int rbase = m0 + wy * 64 + mf * 16 + quad * 4;
#pragma unroll
            for (int r = 0; r < 4; r++) {
                int row = rbase + r;
                float part = 0.f, pv[4];
#pragma unroll
                for (int nf = 0; nf < 4; nf++) {
                    int col = n0 + wx * 64 + nf * 16 + l16;
                    float e = (col <= row) ? __expf(acc[mf][nf][r] * scale) : 0.f;
                    pv[nf] = e;
                    part += e;
                }
                // reduce over the 16 l16-lanes of this quad group
                part += __shfl_xor(part, 1, 64);
                part += __shfl_xor(part, 2, 64);
                part += __shfl_xor(part, 4, 64);
                part += __shfl_xor(part, 8, 64);
                if (l16 == 0) atomicAdd(&rs[row], part);
#pragma unroll
                for (int nf = 0; nf < 4; nf++) {
                    int col = n0 + wx * 64 + nf * 16 + l16;
                    C[(size_t)row * ldc + col] = __float2bfloat16(pv[nf]);
                }
            }
        }
    } else {
        // normalize by row sum, fp32 store
        float* C = (float*)Cbase + (size_t)z * sC;
        const float* rs = aux + (size_t)z * TT;
#pragma unroll
        for (int mf = 0; mf < 4; mf++) {
            int rbase = m0 + wy * 64 + mf * 16 + quad * 4;
#pragma unroll
            for (int r = 0; r < 4; r++) {
                int row = rbase + r;
                float inv = 1.f / rs[row];
#pragma unroll
                for (int nf = 0; nf < 4; nf++) {
                    int col = n0 + wx * 64 + nf * 16 + l16;
                    C[(size_t)row * ldc + col] = acc[mf][nf][r] * inv;
                }
            }
        }
    }
}

// ---------------------------------------------------------------------------
// x (fp32) -> bf16, 4 elems/thread vectorized
// ---------------------------------------------------------------------------
__global__ __launch_bounds__(256) void cvt_x(const float* __restrict__ in,
                                             unsigned short* __restrict__ out)
{
    size_t i = ((size_t)blockIdx.x * 256 + threadIdx.x) * 4;
    float4 f = *(const float4*)(in + i);
    union { u16x4 u; __hip_bfloat16 h[4]; } o;
    o.h[0] = __float2bfloat16(f.x);
    o.h[1] = __float2bfloat16(f.y);
    o.h[2] = __float2bfloat16(f.z);
    o.h[3] = __float2bfloat16(f.w);
    *(u16x4*)(out + i) = o.u;
}

// ---------------------------------------------------------------------------
// W (DxD fp32, row-major [c][h]) -> Wt (bf16, [h][c]); z selects Wk/Wq/Wv
// ---------------------------------------------------------------------------
__global__ __launch_bounds__(256) void transpose_cvt_w(
    const float* __restrict__ Wk, const float* __restrict__ Wq,
    const float* __restrict__ Wv, __hip_bfloat16* __restrict__ Wt)
{
    const float* W = blockIdx.z == 0 ? Wk : (blockIdx.z == 1 ? Wq : Wv);
    __hip_bfloat16* o = Wt + (size_t)blockIdx.z * DD * DD;
    int h0 = blockIdx.x * 32, c0 = blockIdx.y * 32;
    __shared__ float tl[32][33];
    int tx = threadIdx.x, ty = threadIdx.y;
#pragma unroll
    for (int k = 0; k < 4; k++)
        tl[ty + 8 * k][tx] = W[(size_t)(c0 + ty + 8 * k) * DD + h0 + tx];
    __syncthreads();
#pragma unroll
    for (int k = 0; k < 4; k++)
        o[(size_t)(h0 + ty + 8 * k) * DD + c0 + tx] = __float2bfloat16(tl[tx][ty + 8 * k]);
}

// ---------------------------------------------------------------------------
extern "C" void kernel_launch(void* const* d_in, const int* in_sizes, int n_in,
                              void* d_out, int out_size, void* d_ws, size_t ws_size,
                              hipStream_t stream)
{
    const float* x  = (const float*)d_in[0];
    const float* Wk = (const float*)d_in[1];
    const float* Wq = (const float*)d_in[2];
    const float* Wv = (const float*)d_in[3];
    float* out = (float*)d_out;

    // workspace layout (bytes) — min footprint 140,509,184 B (known to fit, r2/r3):
    //   k    @ 0           : 33,554,432 B bf16
    //   q    @  33,554,432 : 33,554,432 B bf16
    //   vT2  @  67,108,864 : 33,554,432 B bf16 [d][b*T+t]
    //   wt   @ 100,663,296 :  6,291,456 B bf16 [k,q,v]; dead after proj ->
    //   rsum @ 100,663,296 : g*8,192 B fp32 row sums (overlays wt)
    //   xb   @ 106,954,752 : 33,554,432 B bf16; dead after proj ->
    //   P'   @ 106,954,752 : g*8,388,608 B bf16 exp(S) (overlays xb)
    char* ws = (char*)d_ws;
    __hip_bfloat16* kk   = (__hip_bfloat16*)ws;
    __hip_bfloat16* qq   = (__hip_bfloat16*)(ws + 33554432);
    __hip_bfloat16* vT2  = (__hip_bfloat16*)(ws + 67108864);
    __hip_bfloat16* wt   = (__hip_bfloat16*)(ws + 100663296);
    float*          rsum = (float*)         (ws + 100663296);
    __hip_bfloat16* xb   = (__hip_bfloat16*)(ws + 106954752);
    __hip_bfloat16* Pp   = (__hip_bfloat16*)(ws + 106954752);

    // batch group size (deterministic from ws_size): g=8 needs 174,063,616 B
    int g = (ws_size >= 106954752ull + 8ull * 8388608ull) ? 8 : 4;

    // 1. convert inputs to bf16 (W transposed to B^T layout)
    cvt_x<<<16384, 256, 0, stream>>>(x, (unsigned short*)xb);
    transpose_cvt_w<<<dim3(32, 32, 3), dim3(32, 8), 0, stream>>>(Wk, Wq, Wv, wt);

    // 2. K,Q = x @ W{k,q}  (M=16384,N=1024,K=1024). swapMN=1: A-panel XCD-local.
    gemm_bt<0, __hip_bfloat16><<<dim3(128, 8, 2), 256, 0, stream>>>(
        xb, wt, (void*)kk, 1024, 1024, 1024, 1024,
        0LL, 1048576LL, 16777216LL, 1.0f, 0, 0, 1, nullptr);

    // 3. vT2 = Wv^T @ x^T -> [d][b*T+t] directly (big xb operand on fast dim)
    gemm_bt<0, __hip_bfloat16><<<dim3(128, 8, 1), 256, 0, stream>>>(
        wt + 2 * 1048576, xb, (void*)vT2, 1024, 1024, 1024, 16384,
        0LL, 0LL, 0LL, 1.0f, 0, 0, 0, nullptr);

    // 4..5 per batch group
    for (int g0 = 0; g0 < BB; g0 += g) {
        hipMemsetAsync(rsum, 0, (size_t)g * TT * 4, stream);

        // 4. P' = exp(Q K^T / 32) causal-masked, bf16; row sums -> rsum.
        //    Above-diagonal tiles skipped (never read downstream).
        gemm_bt<1, __hip_bfloat16><<<dim3(16, 16, g), 256, 0, stream>>>(
            qq + (size_t)g0 * 2097152, kk + (size_t)g0 * 2097152, (void*)Pp,
            1024, 1024, 1024, 2048,
            2097152LL, 2097152LL, 4194304LL, 0.03125f, 1, 0, 0, rsum);

        // 5. out = (P' @ V) / rowsum  (causal K-stop; P'-panels XCD-local)
        gemm_bt<2, float><<<dim3(16, 8, g), 256, 0, stream>>>(
            Pp, vT2 + (size_t)g0 * 2048, (void*)(out + (size_t)g0 * 2097152),
            2048, 2048, 16384, 1024,
            4194304LL, 2048LL, 2097152LL, 1.0f, 0, 1, 1, rsum);
    }
}

// Round 5
// 354.946 us; speedup vs baseline: 1.2886x; 1.0267x over previous
//
#include <hip/hip_runtime.h>
#include <hip/hip_bf16.h>

// Shapes fixed by the reference: B=8, T=2048, D=1024.
#define BB 8
#define TT 2048
#define DD 1024

typedef __attribute__((ext_vector_type(8))) short short8;
typedef __attribute__((ext_vector_type(4))) float f32x4;
typedef __attribute__((ext_vector_type(4))) unsigned short u16x4;

__device__ inline void gload_lds16(const void* g, void* l) {
    // async global->LDS, width 16B: dest = wave-uniform base + lane*16
    __builtin_amdgcn_global_load_lds((const __attribute__((address_space(1))) void*)g,
                                     (__attribute__((address_space(3))) void*)l, 16, 0, 0);
}

// ---------------------------------------------------------------------------
// Shared 128x128-tile bf16 MFMA GEMM core, BK=64. One call site per kernel
// (static __shared__ inside). 4 waves x 64x64, 16x16x32 MFMA, width-16
// global_load_lds staging, 8-chunk XOR swizzle (0 bank conflicts, r3 PMC).
// MODE 0: C[CT] = scale * acc
// MODE 1: C[bf16] = exp(scale*acc) causal-masked; atomicAdd row sums into rs
// MODE 2: C[f32] = acc / rs[row]
// ---------------------------------------------------------------------------
template<int MODE, typename CT>
__device__ __forceinline__ void gemm_core(
    const __hip_bfloat16* __restrict__ A,
    const __hip_bfloat16* __restrict__ Bt,
    void* __restrict__ Cbase,
    int lda, int ldb, int ldc,
    int m0, int n0, int kmax,
    float scale, float* __restrict__ rs)
{
    __shared__ __align__(16) __hip_bfloat16 lsA[128 * 64];
    __shared__ __align__(16) __hip_bfloat16 lsB[128 * 64];

    const int t    = threadIdx.x;
    const int w    = t >> 6;
    const int l    = t & 63;
    const int quad = l >> 4;
    const int l16  = l & 15;
    const int wy   = w >> 1;   // wave row (0..1), wave tile 64x64
    const int wx   = w & 1;    // wave col

    f32x4 acc[4][4];
#pragma unroll
    for (int i = 0; i < 4; i++)
#pragma unroll
        for (int j = 0; j < 4; j++) acc[i][j] = f32x4{0.f, 0.f, 0.f, 0.f};

    for (int k0 = 0; k0 < kmax; k0 += 64) {
        // stage A (128x64) and Bt (128x64): 4 rounds x 256 lanes x 16B
#pragma unroll
        for (int p = 0; p < 4; p++) {
            int c   = p * 256 + t;          // slot index 0..1023
            int row = c >> 3;               // 8 slots (chunks) per row
            int gch = (c & 7) ^ (row & 7);  // XOR swizzle
            const __hip_bfloat16* ga = A  + (size_t)(m0 + row) * lda + (k0 + gch * 8);
            const __hip_bfloat16* gb = Bt + (size_t)(n0 + row) * ldb + (k0 + gch * 8);
            char* la = (char*)lsA + p * 4096 + w * 1024;
            char* lb = (char*)lsB + p * 4096 + w * 1024;
            gload_lds16(ga, la);
            gload_lds16(gb, lb);
        }
        __syncthreads();

#pragma unroll
        for (int h = 0; h < 2; h++) {      // two K=32 halves
            short8 aF[4], bF[4];
#pragma unroll
            for (int mf = 0; mf < 4; mf++) {
                int m = wy * 64 + mf * 16 + l16;
                aF[mf] = *(const short8*)((const char*)lsA + m * 128 +
                                          (((h * 4 + quad) ^ (m & 7)) * 16));
            }
#pragma unroll
            for (int nf = 0; nf < 4; nf++) {
                int n = wx * 64 + nf * 16 + l16;
                bF[nf] = *(const short8*)((const char*)lsB + n * 128 +
                                          (((h * 4 + quad) ^ (n & 7)) * 16));
            }
#pragma unroll
            for (int mf = 0; mf < 4; mf++)
#pragma unroll
                for (int nf = 0; nf < 4; nf++)
                    acc[mf][nf] = __builtin_amdgcn_mfma_f32_16x16x32_bf16(
                        aF[mf], bF[nf], acc[mf][nf], 0, 0, 0);
        }
        __syncthreads();
    }

    // epilogue: C/D layout col = lane&15, row = quad*4 + reg
    if constexpr (MODE == 0) {
        CT* C = (CT*)Cbase;
#pragma unroll
        for (int mf = 0; mf < 4; mf++) {
            int rbase = m0 + wy * 64 + mf * 16 + quad * 4;
#pragma unroll
            for (int nf = 0; nf < 4; nf++) {
                int col = n0 + wx * 64 + nf * 16 + l16;
#pragma unroll
                for (int r = 0; r < 4; r++) {
                    float v = acc[mf][nf][r] * scale;
                    if constexpr (sizeof(CT) == 2)
                        C[(size_t)(rbase + r) * ldc + col] = (CT)__float2bfloat16(v);
                    else
                        *((float*)&C[(size_t)(rbase + r) * ldc + col]) = v;
                }
            }
        }
    } else if constexpr (MODE == 1) {
        __hip_bfloat16* C = (__hip_bfloat16*)Cbase;
#pragma unroll
        for (int mf = 0; mf < 4; mf++) {
            int rbase = m0 + wy * 64 + mf * 16 + quad * 4;
#pragma unroll
            for (int r = 0; r < 4; r++) {
                int row = rbase + r;
                float part = 0.f, pv[4];
#pragma unroll
                for (int nf = 0; nf < 4; nf++) {
                    int col = n0 + wx * 64 + nf * 16 + l16;
                    float e = (col <= row) ? __expf(acc[mf][nf][r] * scale) : 0.f;
                    pv[nf] = e;
                    part += e;
                }
                part += __shfl_xor(part, 1, 64);
                part += __shfl_xor(part, 2, 64);
                part += __shfl_xor(part, 4, 64);
                part += __shfl_xor(part, 8, 64);
                if (l16 == 0) atomicAdd(&rs[row], part);
#pragma unroll
                for (int nf = 0; nf < 4; nf++) {
                    int col = n0 + wx * 64 + nf * 16 + l16;
                    C[(size_t)row * ldc + col] = __float2bfloat16(pv[nf]);
                }
            }
        }
    } else {
        float* C = (float*)Cbase;
#pragma unroll
        for (int mf = 0; mf < 4; mf++) {
            int rbase = m0 + wy * 64 + mf * 16 + quad * 4;
#pragma unroll
            for (int r = 0; r < 4; r++) {
                int row = rbase + r;
                float inv = 1.f / rs[row];
#pragma unroll
                for (int nf = 0; nf < 4; nf++) {
                    int col = n0 + wx * 64 + nf * 16 + l16;
                    C[(size_t)row * ldc + col] = acc[mf][nf][r] * inv;
                }
            }
        }
    }
}

// ---------------------------------------------------------------------------
// Fused projection dispatch: z=0,1 -> K,Q = x @ W{k,q} (swapMN: m-tile on x,
// A-panel XCD-local); z=2 -> vT2 = Wv^T @ x^T (n-tile on x, xb XCD-local).
// ---------------------------------------------------------------------------
__global__ __launch_bounds__(256, 3) void proj3(
    const __hip_bfloat16* __restrict__ xb,
    const __hip_bfloat16* __restrict__ wt,
    __hip_bfloat16* __restrict__ kq,
    __hip_bfloat16* __restrict__ vT2)
{
    const int z = blockIdx.z;
    const __hip_bfloat16 *A, *Bt;
    void* C;
    int ldc, m0, n0;
    if (z < 2) {
        A = xb; Bt = wt + z * 1048576; C = kq + (size_t)z * 16777216;
        ldc = 1024; m0 = blockIdx.x * 128; n0 = blockIdx.y * 128;
    } else {
        A = wt + 2 * 1048576; Bt = xb; C = vT2;
        ldc = 16384; m0 = blockIdx.y * 128; n0 = blockIdx.x * 128;
    }
    gemm_core<0, __hip_bfloat16>(A, Bt, C, 1024, 1024, ldc, m0, n0, 1024, 1.0f, nullptr);
}

// ---------------------------------------------------------------------------
// Attention GEMMs. permX: bx -> (bx<8 ? 15-bx : bx-8). With gridDim.x=16 and
// XCD = linear%8 = bx%8, XCD d hosts x-tiles {15-d, d}: S-GEMM working blocks
// per XCD = (1+d)+(16-d) = 17 = const; PV K-tile sum = (16-d)+(d+1) = const.
// Kills the 1.41x XCD imbalance of identity ordering (r4 analysis).
// ---------------------------------------------------------------------------
template<int MODE, typename CT>
__global__ __launch_bounds__(256, 3) void gemm_bt(
    const __hip_bfloat16* __restrict__ Abase,
    const __hip_bfloat16* __restrict__ Btbase,
    void* __restrict__ Cbase,
    int K, int lda, int ldb, int ldc,
    long long sA, long long sB, long long sC,
    float scale, int causalSkip, int causalKStop, int swapMN, int permX,
    float* __restrict__ aux)
{
    int bx = blockIdx.x;
    if (permX) bx = (bx < 8) ? 15 - bx : bx - 8;
    const int m0 = (swapMN ? bx : blockIdx.y) * 128;
    const int n0 = (swapMN ? blockIdx.y : bx) * 128;
    if (causalSkip && n0 > m0) return;

    const int z = blockIdx.z;
    int kmax = K;
    if (causalKStop) { int km = m0 + 128; kmax = km < K ? km : K; }

    gemm_core<MODE, CT>(Abase + (size_t)z * sA, Btbase + (size_t)z * sB,
                        (char*)Cbase + (size_t)z * sC * sizeof(CT),
                        lda, ldb, ldc, m0, n0, kmax, scale,
                        aux ? aux + (size_t)z * TT : nullptr);
}

// ---------------------------------------------------------------------------
// x (fp32) -> bf16, 4 elems/thread vectorized
// ---------------------------------------------------------------------------
__global__ __launch_bounds__(256) void cvt_x(const float* __restrict__ in,
                                             unsigned short* __restrict__ out)
{
    size_t i = ((size_t)blockIdx.x * 256 + threadIdx.x) * 4;
    float4 f = *(const float4*)(in + i);
    union { u16x4 u; __hip_bfloat16 h[4]; } o;
    o.h[0] = __float2bfloat16(f.x);
    o.h[1] = __float2bfloat16(f.y);
    o.h[2] = __float2bfloat16(f.z);
    o.h[3] = __float2bfloat16(f.w);
    *(u16x4*)(out + i) = o.u;
}

// ---------------------------------------------------------------------------
// W (DxD fp32, row-major [c][h]) -> Wt (bf16, [h][c]); z selects Wk/Wq/Wv
// ---------------------------------------------------------------------------
__global__ __launch_bounds__(256) void transpose_cvt_w(
    const float* __restrict__ Wk, const float* __restrict__ Wq,
    const float* __restrict__ Wv, __hip_bfloat16* __restrict__ Wt)
{
    const float* W = blockIdx.z == 0 ? Wk : (blockIdx.z == 1 ? Wq : Wv);
    __hip_bfloat16* o = Wt + (size_t)blockIdx.z * DD * DD;
    int h0 = blockIdx.x * 32, c0 = blockIdx.y * 32;
    __shared__ float tl[32][33];
    int tx = threadIdx.x, ty = threadIdx.y;
#pragma unroll
    for (int k = 0; k < 4; k++)
        tl[ty + 8 * k][tx] = W[(size_t)(c0 + ty + 8 * k) * DD + h0 + tx];
    __syncthreads();
#pragma unroll
    for (int k = 0; k < 4; k++)
        o[(size_t)(h0 + ty + 8 * k) * DD + c0 + tx] = __float2bfloat16(tl[tx][ty + 8 * k]);
}

// ---------------------------------------------------------------------------
extern "C" void kernel_launch(void* const* d_in, const int* in_sizes, int n_in,
                              void* d_out, int out_size, void* d_ws, size_t ws_size,
                              hipStream_t stream)
{
    const float* x  = (const float*)d_in[0];
    const float* Wk = (const float*)d_in[1];
    const float* Wq = (const float*)d_in[2];
    const float* Wv = (const float*)d_in[3];
    float* out = (float*)d_out;

    // workspace layout (bytes):
    //   k    @ 0           : 33,554,432 B bf16
    //   q    @  33,554,432 : 33,554,432 B bf16
    //   vT2  @  67,108,864 : 33,554,432 B bf16 [d][b*T+t]
    //   wt   @ 100,663,296 :  6,291,456 B bf16 [k,q,v]; dead after proj ->
    //   rsum @ 100,663,296 : g*8,192 B fp32 row sums (overlays wt)
    //   xb   @ 106,954,752 : 33,554,432 B bf16; dead after proj ->
    //   P'   @ 106,954,752 : g*8,388,608 B bf16 exp(S) (overlays xb)
    char* ws = (char*)d_ws;
    __hip_bfloat16* kk   = (__hip_bfloat16*)ws;
    __hip_bfloat16* qq   = (__hip_bfloat16*)(ws + 33554432);
    __hip_bfloat16* vT2  = (__hip_bfloat16*)(ws + 67108864);
    __hip_bfloat16* wt   = (__hip_bfloat16*)(ws + 100663296);
    float*          rsum = (float*)         (ws + 100663296);
    __hip_bfloat16* xb   = (__hip_bfloat16*)(ws + 106954752);
    __hip_bfloat16* Pp   = (__hip_bfloat16*)(ws + 106954752);

    // batch group size (deterministic from ws_size): g=8 needs 174,063,616 B
    int g = (ws_size >= 106954752ull + 8ull * 8388608ull) ? 8 : 4;

    // 1. convert inputs to bf16 (W transposed to B^T layout)
    cvt_x<<<16384, 256, 0, stream>>>(x, (unsigned short*)xb);
    transpose_cvt_w<<<dim3(32, 32, 3), dim3(32, 8), 0, stream>>>(Wk, Wq, Wv, wt);

    // 2. K,Q,vT all in one dispatch (z=0,1: x@W; z=2: Wv^T@x^T)
    proj3<<<dim3(128, 8, 3), 256, 0, stream>>>(xb, wt, kk, vT2);

    // 3..4 per batch group
    for (int g0 = 0; g0 < BB; g0 += g) {
        hipMemsetAsync(rsum, 0, (size_t)g * TT * 4, stream);

        // 3. P' = exp(Q K^T / 32) causal-masked, bf16; row sums -> rsum.
        //    permX balances causal-skip work across XCDs.
        gemm_bt<1, __hip_bfloat16><<<dim3(16, 16, g), 256, 0, stream>>>(
            qq + (size_t)g0 * 2097152, kk + (size_t)g0 * 2097152, (void*)Pp,
            1024, 1024, 1024, 2048,
            2097152LL, 2097152LL, 4194304LL, 0.03125f, 1, 0, 0, 1, rsum);

        // 4. out = (P' @ V) / rowsum  (causal K-stop; permX balances K-length
        //    across XCDs and dispatches long m-tiles first)
        gemm_bt<2, float><<<dim3(16, 8, g), 256, 0, stream>>>(
            Pp, vT2 + (size_t)g0 * 2048, (void*)(out + (size_t)g0 * 2097152),
            2048, 2048, 16384, 1024,
            4194304LL, 2048LL, 2097152LL, 1.0f, 0, 1, 1, 1, rsum);
    }
}